// Round 4
// baseline (251.880 us; speedup 1.0000x reference)
//
#include <hip/hip_runtime.h>

// CatNet_76553497084407 — SLAYER-style spiking CNN, fully collapsed over time.
//
// Only spike COUNTS flow between layers, so T=50 is never materialized.
// R4: LDS-pipe attack. Conv inputs stored channel-minor (transposed) with
// bank-coprime padded row strides, so conv2/conv3 windows are read as
// ds_read_b128 (4x fewer LDS instructions, BW-limited not issue-limited).
// conv2 serves 8 output channels per thread (halves reads per output).

#define T_STEPS 50
#define THETA   0.9999f

__device__ __forceinline__ float spike_rate(float a) {
    constexpr float INV = 50.0f / 0.9999f;
    float t = a * INV;
    float c = fminf(fmaxf(floorf(t), 0.0f), 50.0f);
    // fall back to the exact 50-step f32 sim when t is near an integer
    bool risky = (t > 0.5f) && (fabsf(t - rintf(t)) < 5e-4f);
    if (__ballot(risky)) {
        float v = 0.f, cnt = 0.f;
#pragma unroll 1
        for (int k = 0; k < T_STEPS; ++k) {
            v += a;
            float s = (v >= THETA) ? 1.0f : 0.0f;
            v -= s * THETA;
            cnt += s;
        }
        c = cnt;
    }
    return c / 50.0f;   // true divide: match reference sum/T rounding
}

extern "C" __global__ void __launch_bounds__(1024)
catnet_kernel(const float* __restrict__ x,
              const float* __restrict__ w1, const float* __restrict__ b1,
              const float* __restrict__ w2, const float* __restrict__ b2,
              const float* __restrict__ w3, const float* __restrict__ b3,
              const float* __restrict__ wf, const float* __restrict__ bf,
              float* __restrict__ out)
{
    const int n    = blockIdx.x;
    const int tid  = threadIdx.x;
    const int wave = tid >> 6;
    const int lane = tid & 63;

    __shared__ float xbar[182];          // [h+1]
    __shared__ float r1t[182][20];       // [h+1][ci], 16 ci + pad4 (rows 80B, bank-step 5)
    __shared__ float r2s[32][174];
    __shared__ float r3t[89][36];        // [h+1][ci], 32 ci + pad4 (rows 144B, bank-step 9)
    __shared__ float r4s[32][83];
    __shared__ float part[16];

    // zero conv pad rows
    if (tid < 20)               { r1t[0][tid] = 0.f; r1t[181][tid] = 0.f; }
    if (tid >= 32 && tid < 68)  { r3t[0][tid-32] = 0.f; r3t[88][tid-32] = 0.f; }
    if (tid == 127)             { xbar[0] = 0.f; xbar[181] = 0.f; }

    // ---- phase 0: time-sum of input, 4 lanes per h ----
    const float* xn = x + (size_t)n * (180 * 50);
    if (tid < 720) {
        const int h = tid >> 2, q = tid & 3;
        const float* row = xn + h * 50;
        float s = 0.f;
        for (int t = q; t < T_STEPS; t += 4) s += row[t];
        s += __shfl_xor(s, 1, 4);
        s += __shfl_xor(s, 2, 4);
        if (q == 0) xbar[h + 1] = s;
    }
    __syncthreads();

    // ---- phase 1: conv1 (1->16, k=3, pad=1), /T, +b1, rate -> r1t ----
    for (int idx = tid; idx < 16 * 180; idx += 1024) {
        int c = idx / 180, h = idx - c * 180;
        float a = w1[c*3+0] * xbar[h] + w1[c*3+1] * xbar[h+1] + w1[c*3+2] * xbar[h+2];
        a = a / 50.0f + b1[c];
        r1t[h + 1][c] = spike_rate(a);
    }
    __syncthreads();

    // ---- phase 2: conv2 (16->32, k=9, pad=1) + rate ----
    // 16 waves = 4 out-ch-groups(8) x 4 h-quarters; lanes -> h.
    {
        const int g8  = __builtin_amdgcn_readfirstlane(wave >> 2) * 8;
        const int q   = wave & 3;
        const int lim = (q == 3) ? 42 : 44;
        const bool act = lane < lim;
        const int h0  = q * 44 + lane;        // valid max 173; window max 181
        const int hr  = act ? h0 : 0;

        float a[8];
#pragma unroll
        for (int j = 0; j < 8; ++j) a[j] = b2[g8 + j];

#pragma unroll
        for (int c4 = 0; c4 < 4; ++c4) {
            float rw[9][4];
#pragma unroll
            for (int kh = 0; kh < 9; ++kh) {
                float4 t = *(const float4*)&r1t[hr + kh][c4 * 4];
                rw[kh][0] = t.x; rw[kh][1] = t.y; rw[kh][2] = t.z; rw[kh][3] = t.w;
            }
#pragma unroll
            for (int j = 0; j < 8; ++j) {
                const float* wj = w2 + ((g8 + j) * 16 + c4 * 4) * 9;
#pragma unroll
                for (int u = 0; u < 4; ++u) {
#pragma unroll
                    for (int kh = 0; kh < 9; ++kh)
                        a[j] += wj[u * 9 + kh] * rw[kh][u];
                }
            }
        }
#pragma unroll
        for (int j = 0; j < 8; ++j) {
            float r = spike_rate(a[j]);
            if (act) r2s[g8 + j][h0] = r;
        }
    }
    __syncthreads();

    // ---- phase 3: sum-pool(2,1) * 1.1 + rate -> r3t ----
    for (int idx = tid; idx < 32 * 87; idx += 1024) {
        int c = idx / 87, h = idx - c * 87;
        float a = 1.1f * (r2s[c][2*h] + r2s[c][2*h + 1]);
        r3t[h + 1][c] = spike_rate(a);
    }
    __syncthreads();

    // ---- phase 4: conv3 (32->32, k=7, pad=1) + rate ----
    // 16 waves = 8 out-ch-groups(4) x 2 h-halves; lanes -> h.
    {
        const int g4   = __builtin_amdgcn_readfirstlane(wave >> 1) * 4;
        const int half = wave & 1;
        const int cnt  = half ? 41 : 42;
        const bool act = lane < cnt;
        const int h0   = half * 42 + lane;    // valid max 82; window max 88
        const int hr   = act ? h0 : 0;

        float a[4];
#pragma unroll
        for (int j = 0; j < 4; ++j) a[j] = b3[g4 + j];

#pragma unroll
        for (int c4 = 0; c4 < 8; ++c4) {
            float rw[7][4];
#pragma unroll
            for (int kh = 0; kh < 7; ++kh) {
                float4 t = *(const float4*)&r3t[hr + kh][c4 * 4];
                rw[kh][0] = t.x; rw[kh][1] = t.y; rw[kh][2] = t.z; rw[kh][3] = t.w;
            }
#pragma unroll
            for (int j = 0; j < 4; ++j) {
                const float* wj = w3 + ((g4 + j) * 32 + c4 * 4) * 7;
#pragma unroll
                for (int u = 0; u < 4; ++u) {
#pragma unroll
                    for (int kh = 0; kh < 7; ++kh)
                        a[j] += wj[u * 7 + kh] * rw[kh][u];
                }
            }
        }
#pragma unroll
        for (int j = 0; j < 4; ++j) {
            float r = spike_rate(a[j]);
            if (act) r4s[g4 + j][h0] = r;
        }
    }
    __syncthreads();

    // ---- phase 5: dense [32*83] -> 4 outputs; 4 waves per output ----
    {
        const int o = wave >> 2, q = wave & 3;
        const float* r4f = &r4s[0][0];
        const float* wo  = wf + o * (32 * 83);
        float acc = 0.f;
        for (int j = q * 64 + lane; j < 32 * 83; j += 256)
            acc += r4f[j] * wo[j];
#pragma unroll
        for (int off = 32; off > 0; off >>= 1)
            acc += __shfl_down(acc, off, 64);
        if (lane == 0) part[wave] = acc;
    }
    __syncthreads();
    if (tid < 4) {
        float s = part[tid*4] + part[tid*4+1] + part[tid*4+2] + part[tid*4+3];
        out[n * 4 + tid] = s + bf[tid];
    }
}

extern "C" void kernel_launch(void* const* d_in, const int* in_sizes, int n_in,
                              void* d_out, int out_size, void* d_ws, size_t ws_size,
                              hipStream_t stream) {
    const float* x  = (const float*)d_in[0];
    const float* w1 = (const float*)d_in[1];
    const float* b1 = (const float*)d_in[2];
    const float* w2 = (const float*)d_in[3];
    const float* b2 = (const float*)d_in[4];
    const float* w3 = (const float*)d_in[5];
    const float* b3 = (const float*)d_in[6];
    const float* wf = (const float*)d_in[7];
    const float* bf = (const float*)d_in[8];
    float* outp = (float*)d_out;

    catnet_kernel<<<dim3(256), dim3(1024), 0, stream>>>(
        x, w1, b1, w2, b2, w3, b3, wf, bf, outp);
}

// Round 6
// 209.324 us; speedup vs baseline: 1.2033x; 1.2033x over previous
//
#include <hip/hip_runtime.h>

// CatNet_76553497084407 — SLAYER-style spiking CNN, fully collapsed over time.
//
// Only spike COUNTS flow between layers, so T=50 is never materialized.
// R4/R5 lesson: the b128 channel-minor layout is right, but holding the full
// 9x4 window + 8 accumulators spilled to scratch (VGPR cap 64), causing a 6x
// regression and a graph-replay divergence. R6: STREAMING window — one float4
// live at a time, ~20 live VGPRs, no scratch. Plain __launch_bounds__(1024)
// (the configuration that passed R2-R4).

#define T_STEPS 50
#define THETA   0.9999f

__device__ __forceinline__ float spike_rate(float a) {
    constexpr float INV = 50.0f / 0.9999f;
    float t = a * INV;
    float c = fminf(fmaxf(floorf(t), 0.0f), 50.0f);
    // fall back to the exact 50-step f32 sim when t is near an integer
    bool risky = (t > 0.5f) && (fabsf(t - rintf(t)) < 5e-4f);
    if (__ballot(risky)) {
        float v = 0.f, cnt = 0.f;
#pragma unroll 1
        for (int k = 0; k < T_STEPS; ++k) {
            v += a;
            float s = (v >= THETA) ? 1.0f : 0.0f;
            v -= s * THETA;
            cnt += s;
        }
        c = cnt;
    }
    return c / 50.0f;   // true divide: match reference sum/T rounding
}

extern "C" __global__ void __launch_bounds__(1024)
catnet_kernel(const float* __restrict__ x,
              const float* __restrict__ w1, const float* __restrict__ b1,
              const float* __restrict__ w2, const float* __restrict__ b2,
              const float* __restrict__ w3, const float* __restrict__ b3,
              const float* __restrict__ wf, const float* __restrict__ bf,
              float* __restrict__ out)
{
    const int n    = blockIdx.x;
    const int tid  = threadIdx.x;
    const int wave = tid >> 6;
    const int lane = tid & 63;

    __shared__ float xbar[182];          // [h+1]
    __shared__ float r1t[182][20];       // [h+1][ci], 16 ci + pad4 (rows 80B, bank-step 5)
    __shared__ float r2s[32][174];
    __shared__ float r3t[89][36];        // [h+1][ci], 32 ci + pad4 (rows 144B, bank-step 9)
    __shared__ float r4s[32][83];
    __shared__ float part[16];

    // zero conv pad rows
    if (tid < 20)               { r1t[0][tid] = 0.f; r1t[181][tid] = 0.f; }
    if (tid >= 32 && tid < 68)  { r3t[0][tid-32] = 0.f; r3t[88][tid-32] = 0.f; }
    if (tid == 127)             { xbar[0] = 0.f; xbar[181] = 0.f; }

    // ---- phase 0: time-sum of input, 4 lanes per h ----
    const float* xn = x + (size_t)n * (180 * 50);
    if (tid < 720) {
        const int h = tid >> 2, q = tid & 3;
        const float* row = xn + h * 50;
        float s = 0.f;
        for (int t = q; t < T_STEPS; t += 4) s += row[t];
        s += __shfl_xor(s, 1, 4);
        s += __shfl_xor(s, 2, 4);
        if (q == 0) xbar[h + 1] = s;
    }
    __syncthreads();

    // ---- phase 1: conv1 (1->16, k=3, pad=1), /T, +b1, rate -> r1t ----
    for (int idx = tid; idx < 16 * 180; idx += 1024) {
        int c = idx / 180, h = idx - c * 180;
        float a = w1[c*3+0] * xbar[h] + w1[c*3+1] * xbar[h+1] + w1[c*3+2] * xbar[h+2];
        a = a / 50.0f + b1[c];
        r1t[h + 1][c] = spike_rate(a);
    }
    __syncthreads();

    // ---- phase 2: conv2 (16->32, k=9, pad=1) + rate ----
    // 16 waves = 4 out-ch-groups(8) x 4 h-quarters; lanes -> h.
    // Streaming window: one float4 (4 ci) live at a time -> no spills.
    {
        const int g8  = __builtin_amdgcn_readfirstlane((wave >> 2) * 8);
        const int q   = wave & 3;
        const int lim = (q == 3) ? 42 : 44;
        const bool act = lane < lim;
        const int h0  = q * 44 + lane;        // valid max 173; window max 181
        const int hr  = act ? h0 : 0;

        float a[8];
#pragma unroll
        for (int j = 0; j < 8; ++j) a[j] = b2[g8 + j];

#pragma unroll
        for (int c4 = 0; c4 < 4; ++c4) {
#pragma unroll
            for (int kh = 0; kh < 9; ++kh) {
                float4 t = *(const float4*)&r1t[hr + kh][c4 * 4];
#pragma unroll
                for (int j = 0; j < 8; ++j) {
                    const float* wj = w2 + ((g8 + j) * 16 + c4 * 4) * 9 + kh;
                    a[j] += wj[0] * t.x + wj[9] * t.y + wj[18] * t.z + wj[27] * t.w;
                }
            }
        }
#pragma unroll
        for (int j = 0; j < 8; ++j) {
            float r = spike_rate(a[j]);
            if (act) r2s[g8 + j][h0] = r;
        }
    }
    __syncthreads();

    // ---- phase 3: sum-pool(2,1) * 1.1 + rate -> r3t ----
    for (int idx = tid; idx < 32 * 87; idx += 1024) {
        int c = idx / 87, h = idx - c * 87;
        float a = 1.1f * (r2s[c][2*h] + r2s[c][2*h + 1]);
        r3t[h + 1][c] = spike_rate(a);
    }
    __syncthreads();

    // ---- phase 4: conv3 (32->32, k=7, pad=1) + rate ----
    // 16 waves = 8 out-ch-groups(4) x 2 h-halves; lanes -> h. Streaming window.
    {
        const int g4   = __builtin_amdgcn_readfirstlane((wave >> 1) * 4);
        const int half = wave & 1;
        const int cnt  = half ? 41 : 42;
        const bool act = lane < cnt;
        const int h0   = half * 42 + lane;    // valid max 82; window max 88
        const int hr   = act ? h0 : 0;

        float a[4];
#pragma unroll
        for (int j = 0; j < 4; ++j) a[j] = b3[g4 + j];

#pragma unroll
        for (int c4 = 0; c4 < 8; ++c4) {
#pragma unroll
            for (int kh = 0; kh < 7; ++kh) {
                float4 t = *(const float4*)&r3t[hr + kh][c4 * 4];
#pragma unroll
                for (int j = 0; j < 4; ++j) {
                    const float* wj = w3 + ((g4 + j) * 32 + c4 * 4) * 7 + kh;
                    a[j] += wj[0] * t.x + wj[7] * t.y + wj[14] * t.z + wj[21] * t.w;
                }
            }
        }
#pragma unroll
        for (int j = 0; j < 4; ++j) {
            float r = spike_rate(a[j]);
            if (act) r4s[g4 + j][h0] = r;
        }
    }
    __syncthreads();

    // ---- phase 5: dense [32*83] -> 4 outputs; 4 waves per output ----
    {
        const int o = wave >> 2, q = wave & 3;
        const float* r4f = &r4s[0][0];
        const float* wo  = wf + o * (32 * 83);
        float acc = 0.f;
        for (int j = q * 64 + lane; j < 32 * 83; j += 256)
            acc += r4f[j] * wo[j];
#pragma unroll
        for (int off = 32; off > 0; off >>= 1)
            acc += __shfl_down(acc, off, 64);
        if (lane == 0) part[wave] = acc;
    }
    __syncthreads();
    if (tid < 4) {
        float s = part[tid*4] + part[tid*4+1] + part[tid*4+2] + part[tid*4+3];
        out[n * 4 + tid] = s + bf[tid];
    }
}

extern "C" void kernel_launch(void* const* d_in, const int* in_sizes, int n_in,
                              void* d_out, int out_size, void* d_ws, size_t ws_size,
                              hipStream_t stream) {
    const float* x  = (const float*)d_in[0];
    const float* w1 = (const float*)d_in[1];
    const float* b1 = (const float*)d_in[2];
    const float* w2 = (const float*)d_in[3];
    const float* b2 = (const float*)d_in[4];
    const float* w3 = (const float*)d_in[5];
    const float* b3 = (const float*)d_in[6];
    const float* wf = (const float*)d_in[7];
    const float* bf = (const float*)d_in[8];
    float* outp = (float*)d_out;

    catnet_kernel<<<dim3(256), dim3(1024), 0, stream>>>(
        x, w1, b1, w2, b2, w3, b3, wf, bf, outp);
}

// Round 7
// 104.273 us; speedup vs baseline: 2.4156x; 2.0075x over previous
//
#include <hip/hip_runtime.h>

// CatNet_76553497084407 — SLAYER-style spiking CNN, fully collapsed over time.
//
// Only spike COUNTS flow between layers, so T=50 is never materialized.
// R7 = R3 (proven spill-free, 41us) + conv2/pool/rate fusion:
//   pool output p needs conv2 h=2p,2p+1 whose 9-windows share 8 taps ->
//   one thread computes the pair from a 10-tap window, rates, pools in
//   register, writes r3p directly. Kills the r2s buffer, its 5568-slot
//   LDS round-trip, the phase-3 dispatch and one barrier.
// R4-R6 lesson (b128 + full unroll): compiler hoists unrolled LDS loads ->
// >64 live VGPRs -> scratch spills (WRITE_SIZE 190-232MB, 4-6x regression).
// Stay with b32 reads from contiguous rows; keep live sets ~30 regs.

#define T_STEPS 50
#define THETA   0.9999f

__device__ __forceinline__ float spike_rate(float a) {
    constexpr float INV = 50.0f / 0.9999f;
    float t = a * INV;
    float c = fminf(fmaxf(floorf(t), 0.0f), 50.0f);
    // fall back to the exact 50-step f32 sim when t is near an integer
    bool risky = (t > 0.5f) && (fabsf(t - rintf(t)) < 5e-4f);
    if (__ballot(risky)) {
        float v = 0.f, cnt = 0.f;
#pragma unroll 1
        for (int k = 0; k < T_STEPS; ++k) {
            v += a;
            float s = (v >= THETA) ? 1.0f : 0.0f;
            v -= s * THETA;
            cnt += s;
        }
        c = cnt;
    }
    return c / 50.0f;   // true divide: match reference sum/T rounding
}

extern "C" __global__ void __launch_bounds__(1024)
catnet_kernel(const float* __restrict__ x,
              const float* __restrict__ w1, const float* __restrict__ b1,
              const float* __restrict__ w2, const float* __restrict__ b2,
              const float* __restrict__ w3, const float* __restrict__ b3,
              const float* __restrict__ wf, const float* __restrict__ bf,
              float* __restrict__ out)
{
    const int n    = blockIdx.x;
    const int tid  = threadIdx.x;
    const int wave = tid >> 6;
    const int lane = tid & 63;

    __shared__ float xbar[182];        // [h+1], h in [0,180)
    __shared__ float r1p[16][182];     // [c][h+1]  (zero-padded borders)
    __shared__ float r3p[32][89];      // [c][h+1], h in [0,87)
    __shared__ float r4s[32][83];
    __shared__ float part[16];

    // zero conv pads
    if (tid < 16)              { r1p[tid][0] = 0.f; r1p[tid][181] = 0.f; }
    if (tid >= 32 && tid < 64) { r3p[tid-32][0] = 0.f; r3p[tid-32][88] = 0.f; }
    if (tid == 64)             { xbar[0] = 0.f; xbar[181] = 0.f; }

    // ---- phase 0: time-sum of input, 4 lanes per h ----
    const float* xn = x + (size_t)n * (180 * 50);
    if (tid < 720) {
        const int h = tid >> 2, q = tid & 3;
        const float* row = xn + h * 50;
        float s = 0.f;
        for (int t = q; t < T_STEPS; t += 4) s += row[t];
        s += __shfl_xor(s, 1, 4);
        s += __shfl_xor(s, 2, 4);
        if (q == 0) xbar[h + 1] = s;
    }
    __syncthreads();

    // ---- phase 1: conv1 (1->16, k=3, pad=1), /T, +b1, rate ----
    for (int idx = tid; idx < 16 * 180; idx += 1024) {
        int c = idx / 180, h = idx - c * 180;
        float a = w1[c*3+0] * xbar[h] + w1[c*3+1] * xbar[h+1] + w1[c*3+2] * xbar[h+2];
        a = a / 50.0f + b1[c];
        r1p[c][h + 1] = spike_rate(a);
    }
    __syncthreads();

    // ---- phase 2: conv2 (16->32, k=9, pad=1) + rate + pool(2)*1.1 + rate ----
    // 8 groups of 128 threads: g = tid>>7 (wave-uniform), p = tid&127 < 87.
    // Thread computes conv2 at h=2p,2p+1 (shared 10-tap window) for 4 out-ch,
    // rates, pools in-register, writes r3p[c][p+1].
    {
        const int g   = __builtin_amdgcn_readfirstlane(tid >> 7);   // 0..7
        const int p   = tid & 127;
        const bool act = p < 87;
        const int pr  = act ? p : 0;
        const float* wb = w2 + g * 4 * 144;   // [j][ci][kh], j stride 144

        float a0[4], a1[4];
#pragma unroll
        for (int j = 0; j < 4; ++j) { a0[j] = b2[g*4 + j]; a1[j] = a0[j]; }

        for (int ci = 0; ci < 16; ++ci) {
            float w[10];
#pragma unroll
            for (int d = 0; d < 10; ++d)
                w[d] = r1p[ci][2*pr + d];      // padded h index 2p-1 .. 2p+8
#pragma unroll
            for (int j = 0; j < 4; ++j) {
                const float* wj = wb + j * 144 + ci * 9;
#pragma unroll
                for (int kh = 0; kh < 9; ++kh) {
                    float wv = wj[kh];
                    a0[j] += wv * w[kh];       // h = 2p
                    a1[j] += wv * w[kh + 1];   // h = 2p+1
                }
            }
        }
#pragma unroll
        for (int j = 0; j < 4; ++j) {
            float r20 = spike_rate(a0[j]);
            float r21 = spike_rate(a1[j]);
            float r3  = spike_rate(1.1f * (r20 + r21));
            if (act) r3p[g*4 + j][p + 1] = r3;
        }
    }
    __syncthreads();

    // ---- phase 4: conv3 (32->32, k=7, pad=1) + rate ----
    // 16 waves = 8 out-ch-groups(4) x 2 h-halves; lanes -> h.
    {
        const int g4   = __builtin_amdgcn_readfirstlane((wave >> 1) * 4);
        const int half = wave & 1;
        const int cnt  = half ? 41 : 42;
        const bool act = lane < cnt;
        const int h0   = half * 42 + lane;    // valid max 82; window max 88
        const int hr   = act ? h0 : 0;
        const float* wb = w3 + g4 * 224;      // [j][ci][kh], j stride 224

        float a[4];
#pragma unroll
        for (int j = 0; j < 4; ++j) a[j] = b3[g4 + j];

        for (int ci = 0; ci < 32; ++ci) {
            float rv[7];
#pragma unroll
            for (int kh = 0; kh < 7; ++kh) rv[kh] = r3p[ci][hr + kh];
#pragma unroll
            for (int j = 0; j < 4; ++j) {
                const float* wj = wb + j * 224 + ci * 7;
#pragma unroll
                for (int kh = 0; kh < 7; ++kh)
                    a[j] += wj[kh] * rv[kh];
            }
        }
#pragma unroll
        for (int j = 0; j < 4; ++j) {
            float r = spike_rate(a[j]);
            if (act) r4s[g4 + j][h0] = r;
        }
    }
    __syncthreads();

    // ---- phase 5: dense [32*83] -> 4 outputs; 4 waves per output ----
    {
        const int o = wave >> 2, q = wave & 3;
        const float* r4f = &r4s[0][0];
        const float* wo  = wf + o * (32 * 83);
        float acc = 0.f;
        for (int j = q * 64 + lane; j < 32 * 83; j += 256)
            acc += r4f[j] * wo[j];
#pragma unroll
        for (int off = 32; off > 0; off >>= 1)
            acc += __shfl_down(acc, off, 64);
        if (lane == 0) part[wave] = acc;
    }
    __syncthreads();
    if (tid < 4) {
        float s = part[tid*4] + part[tid*4+1] + part[tid*4+2] + part[tid*4+3];
        out[n * 4 + tid] = s + bf[tid];
    }
}

extern "C" void kernel_launch(void* const* d_in, const int* in_sizes, int n_in,
                              void* d_out, int out_size, void* d_ws, size_t ws_size,
                              hipStream_t stream) {
    const float* x  = (const float*)d_in[0];
    const float* w1 = (const float*)d_in[1];
    const float* b1 = (const float*)d_in[2];
    const float* w2 = (const float*)d_in[3];
    const float* b2 = (const float*)d_in[4];
    const float* w3 = (const float*)d_in[5];
    const float* b3 = (const float*)d_in[6];
    const float* wf = (const float*)d_in[7];
    const float* bf = (const float*)d_in[8];
    float* outp = (float*)d_out;

    catnet_kernel<<<dim3(256), dim3(1024), 0, stream>>>(
        x, w1, b1, w2, b2, w3, b3, wf, bf, outp);
}